// Round 4
// baseline (1288.224 us; speedup 1.0000x reference)
//
#include <hip/hip_runtime.h>
#include <hip/hip_fp16.h>

#define N_NODES 100000
#define N_EDGES 3200000
#define NBUCKETS 391          // ceil(100000 / 256); bucket = dst >> 8
#define NCHUNKB 256           // blocks for hist/scatter
#define CHUNK 12500           // N_EDGES / NCHUNKB
#define GBLK 64               // nodes per gather block (4 waves x 16 groups)
#define NGB ((N_NODES + GBLK - 1) / GBLK)   // 1563
// FEATURE == HIDDEN == 128
// edge_index arrives as int32: ei[0..E) = src, ei[E..2E) = dst.

typedef __attribute__((ext_vector_type(8))) short sh8;   // 8 bf16 (4 VGPRs)
typedef __attribute__((ext_vector_type(4))) float fl4;   // MFMA acc
typedef __attribute__((ext_vector_type(4))) float f4v;   // nontemporal float4 store

// split fp32 into bf16 hi + bf16 lo (both round-to-nearest-even)
__device__ inline void split_bf16(float x, short& hi, short& lo) {
    unsigned u = __float_as_uint(x);
    unsigned r = u + 0x7FFFu + ((u >> 16) & 1u);
    hi = (short)(r >> 16);
    float hif = __uint_as_float(r & 0xFFFF0000u);
    float lof = x - hif;
    unsigned u2 = __float_as_uint(lof);
    lo = (short)((u2 + 0x7FFFu + ((u2 >> 16) & 1u)) >> 16);
}

// ---------------- bucketed CSR build ----------------

__global__ __launch_bounds__(256) void k_bhist(const int* __restrict__ ei_dst,
                                               int* __restrict__ bucket_cnt) {
    __shared__ int h[NBUCKETS];
    int t = threadIdx.x;
    for (int i = t; i < NBUCKETS; i += 256) h[i] = 0;
    __syncthreads();
    int base = blockIdx.x * CHUNK;
    for (int i = t; i < CHUNK; i += 256)
        atomicAdd(&h[ei_dst[base + i] >> 8], 1);
    __syncthreads();
    for (int i = t; i < NBUCKETS; i += 256)
        if (h[i]) atomicAdd(&bucket_cnt[i], h[i]);
}

__global__ __launch_bounds__(512) void k_bscan(const int* __restrict__ bucket_cnt,
                                               int* __restrict__ bucket_base,
                                               int* __restrict__ bucket_fill) {
    __shared__ int s[512];
    int t = threadIdx.x;
    int v = (t < NBUCKETS) ? bucket_cnt[t] : 0;
    s[t] = v;
    __syncthreads();
    for (int off = 1; off < 512; off <<= 1) {
        int x = (t >= off) ? s[t - off] : 0;
        __syncthreads();
        s[t] += x;
        __syncthreads();
    }
    int ex = s[t] - v;
    if (t < NBUCKETS) { bucket_base[t] = ex; bucket_fill[t] = ex; }
    if (t == NBUCKETS - 1) bucket_base[NBUCKETS] = s[t];
}

// packed entry: src (17 bits) | dstlocal (8 bits) << 17
__global__ __launch_bounds__(256) void k_bscatter(const int* __restrict__ ei,
                                                  int* __restrict__ bucket_fill,
                                                  unsigned* __restrict__ bpairs) {
    __shared__ int h[NBUCKETS];
    __shared__ int basep[NBUCKETS];
    int t = threadIdx.x;
    const int* dstp = ei + N_EDGES;
    int base = blockIdx.x * CHUNK;

    for (int i = t; i < NBUCKETS; i += 256) h[i] = 0;
    __syncthreads();
    for (int i = t; i < CHUNK; i += 256)
        atomicAdd(&h[dstp[base + i] >> 8], 1);
    __syncthreads();
    for (int i = t; i < NBUCKETS; i += 256) {
        int c = h[i];
        basep[i] = c ? atomicAdd(&bucket_fill[i], c) : 0;
    }
    __syncthreads();
    for (int i = t; i < NBUCKETS; i += 256) h[i] = 0;  // reuse as rank
    __syncthreads();
    for (int i = t; i < CHUNK; i += 256) {
        int d = dstp[base + i];
        int s = ei[base + i];
        int b = d >> 8;
        int r = atomicAdd(&h[b], 1);
        bpairs[basep[b] + r] = (unsigned)s | ((unsigned)(d & 255) << 17);
    }
}

__global__ __launch_bounds__(256) void k_bbuild(const unsigned* __restrict__ bpairs,
                                                const int* __restrict__ bucket_base,
                                                int* __restrict__ row_ptr,
                                                int* __restrict__ cnt,
                                                float* __restrict__ dinv,
                                                int* __restrict__ csr_src) {
    __shared__ int h[256];
    __shared__ int sc[256];
    int b = blockIdx.x;
    int t = threadIdx.x;
    int e0 = bucket_base[b], e1 = bucket_base[b + 1];

    h[t] = 0;
    __syncthreads();
    for (int i = e0 + t; i < e1; i += 256)
        atomicAdd(&h[bpairs[i] >> 17], 1);
    __syncthreads();
    int v = h[t];
    sc[t] = v;
    __syncthreads();
    for (int off = 1; off < 256; off <<= 1) {
        int x = (t >= off) ? sc[t - off] : 0;
        __syncthreads();
        sc[t] += x;
        __syncthreads();
    }
    int ex = sc[t] - v;
    int node = b * 256 + t;
    if (node < N_NODES) {
        cnt[node] = v;
        dinv[node] = rsqrtf((float)(v + 1));
        row_ptr[node] = e0 + ex;
    }
    __syncthreads();
    h[t] = e0 + ex;               // absolute fill cursor
    __syncthreads();
    for (int i = e0 + t; i < e1; i += 256) {
        unsigned p = bpairs[i];
        int pos = atomicAdd(&h[p >> 17], 1);
        csr_src[pos] = (int)(p & 0x1FFFFu);
    }
}

// ------- W repack (+ fused bucket_cnt zero in the extra block) -------
// B-frag (16x16x32): lane = q*16 + n16 holds B[k = ks*32 + q*8 + j][n = c*16 + n16],
// j = 0..7 contiguous. Storage: frag[((l*32 + ks*8 + c)*64 + lane)*8 + j].

__global__ __launch_bounds__(256) void k_wprep(const float* __restrict__ W0,
                                               const float* __restrict__ W1,
                                               const float* __restrict__ W2,
                                               short* __restrict__ fhi,
                                               short* __restrict__ flo,
                                               int* __restrict__ bucket_cnt) {
    if (blockIdx.x == 192) {   // fused: zero the bucket counters
        for (int i = threadIdx.x; i < NBUCKETS; i += 256) bucket_cnt[i] = 0;
        return;
    }
    int idx = blockIdx.x * 256 + threadIdx.x;   // 3 * 16384
    int l = idx >> 14, e = idx & 16383;
    const float* W = (l == 0) ? W0 : (l == 1) ? W1 : W2;
    float w = W[e];
    int k = e >> 7, n = e & 127;
    int ks = k >> 5, q = (k >> 3) & 3, j = k & 7;
    int c = n >> 4, n16 = n & 15;
    int lane = q * 16 + n16;
    int dst = ((l * 32 + ks * 8 + c) * 64 + lane) * 8 + j;
    short hi, lo;
    split_bf16(w, hi, lo);
    fhi[dst] = hi;
    flo[dst] = lo;
}

// ------- GEMM v5: H16 = fp16( (X @ W) * dinv[row] ), sliced output layout -------
// H16 is stored FEATURE-SLICED: H16[(slice*N_NODES + row)*16 + n16], slice = feature>>4.
// A-input: standard [row][128] for layer 0 (sliced=0), sliced fp32 for layers 1-2.
// 512 threads = 8 waves, 16 rows/wave -> 128 rows/block; split-bf16 MFMA (3 per acc).

__global__ __launch_bounds__(512, 4) void k_gemm_mfma(const float* __restrict__ X,
                                                      const short* __restrict__ fhi,
                                                      const short* __restrict__ flo,
                                                      const float* __restrict__ dinv,
                                                      __half* __restrict__ H16,
                                                      int sliced) {
    __shared__ short Bh[16384];    // 32 KB
    __shared__ short Bl[16384];    // 32 KB

    int t = threadIdx.x;
    int wave = t >> 6, lane = t & 63;
    int q = lane >> 4, n16 = lane & 15;
    int row_base = blockIdx.x * 128 + wave * 16;

    // hoist all A loads: 4 ks x 32 B per lane (in flight before any use)
    int r0 = row_base + n16;
    if (r0 > N_NODES - 1) r0 = N_NODES - 1;
    float4 a[4][2];
    if (!sliced) {
        const float* p0 = X + (long long)r0 * 128 + q * 8;
#pragma unroll
        for (int ks = 0; ks < 4; ++ks) {
            a[ks][0] = *(const float4*)(p0 + ks * 32);
            a[ks][1] = *(const float4*)(p0 + ks * 32 + 4);
        }
    } else {
        // feature chunk f0 = q*8 + ks*32 lives at slice f0>>4, offset f0&15
#pragma unroll
        for (int ks = 0; ks < 4; ++ks) {
            int sl = ks * 2 + (q >> 1);
            const float* p = X + ((long long)sl * N_NODES + r0) * 16 + (q & 1) * 8;
            a[ks][0] = *(const float4*)p;
            a[ks][1] = *(const float4*)(p + 4);
        }
    }

    // stage B frags into LDS: 2048 float4 per array, 512 threads -> 4 iters
    {
        const float4* sh_ = (const float4*)fhi;
        const float4* sl_ = (const float4*)flo;
        float4* dh = (float4*)Bh;
        float4* dl = (float4*)Bl;
#pragma unroll
        for (int i = 0; i < 4; ++i) {
            dh[t + i * 512] = sh_[t + i * 512];
            dl[t + i * 512] = sl_[t + i * 512];
        }
    }

    // split A into bf16 hi/lo fragments (under vmcnt shadow)
    sh8 ah[4], al[4];
#pragma unroll
    for (int ks = 0; ks < 4; ++ks) {
        float xs[8];
        xs[0] = a[ks][0].x; xs[1] = a[ks][0].y; xs[2] = a[ks][0].z; xs[3] = a[ks][0].w;
        xs[4] = a[ks][1].x; xs[5] = a[ks][1].y; xs[6] = a[ks][1].z; xs[7] = a[ks][1].w;
#pragma unroll
        for (int j = 0; j < 8; ++j) {
            short h, l;
            split_bf16(xs[j], h, l);
            ah[ks][j] = h;
            al[ks][j] = l;
        }
    }

    fl4 acc[8];
#pragma unroll
    for (int c = 0; c < 8; ++c) acc[c] = (fl4){0.f, 0.f, 0.f, 0.f};

    __syncthreads();

    // MFMA loop: pure LDS reads + MFMA (compiler pipelines via lgkmcnt)
#pragma unroll
    for (int ks = 0; ks < 4; ++ks)
#pragma unroll
        for (int c = 0; c < 8; ++c) {
            sh8 bh = *(const sh8*)&Bh[((ks * 8 + c) * 64 + lane) * 8];
            sh8 bl = *(const sh8*)&Bl[((ks * 8 + c) * 64 + lane) * 8];
            acc[c] = __builtin_amdgcn_mfma_f32_16x16x32_bf16(ah[ks], bh, acc[c], 0, 0, 0);
            acc[c] = __builtin_amdgcn_mfma_f32_16x16x32_bf16(al[ks], bh, acc[c], 0, 0, 0);
            acc[c] = __builtin_amdgcn_mfma_f32_16x16x32_bf16(ah[ks], bl, acc[c], 0, 0, 0);
        }

    // epilogue: C/D layout row = q*4 + reg, col = c*16 + n16 -> sliced H16
#pragma unroll
    for (int reg = 0; reg < 4; ++reg) {
        int grow = row_base + q * 4 + reg;
        if (grow < N_NODES) {
            float sc = dinv[grow];
#pragma unroll
            for (int c = 0; c < 8; ++c)
                H16[(c * N_NODES + grow) * 16 + n16] = __float2half(acc[c][reg] * sc);
        }
    }
}

// ---------------- gather aggregation + bias + relu (sliced, no staging) ----------
// blockIdx % 8 = feature slice (pins slice to one XCD; 3.2 MB slice lives in its
// 4 MB L2). Wave = 16 groups x 4 lanes; each GROUP owns one node; lane owns a
// 4-feature quarter (8 B half4 gathers). Per batch: 8 gathers + 8 next-batch idx
// loads issued, then sched_barrier(0) pins the consume cluster AFTER the loads ->
// 16 VMEM in flight per wave. idx loads are nontemporal (csr stream must not evict
// the pinned H slice); no LDS, no syncthreads -> full occupancy.

__global__ __launch_bounds__(256) void k_gather(const __half2* __restrict__ H2,
                                                const int* __restrict__ csr_src,
                                                const int* __restrict__ row_ptr,
                                                const int* __restrict__ cnt,
                                                const float* __restrict__ dinv,
                                                const float* __restrict__ b,
                                                float* __restrict__ out,
                                                int std_out) {
    int s = blockIdx.x & 7;                  // slice -> XCD (round-robin heuristic)
    int grp = blockIdx.x >> 3;
    int t = threadIdx.x;
    int lane = t & 63;
    int g = lane >> 2;                       // group (node) within wave: 0..15
    int q = lane & 3;                        // feature quarter (4 features, 8 B)
    int wv = t >> 6;

    int node = grp * GBLK + wv * 16 + g;
    if (node >= N_NODES) return;

    const char* Hb = (const char*)H2 + (size_t)s * N_NODES * 32;  // 32 B slice rows
    const char* Cb = (const char*)csr_src;
    int start = row_ptr[node];
    int n = cnt[node];
    float dd = dinv[node];
    float4 bb = ((const float4*)b)[s * 4 + q];

    // self contribution (H row already carries dinv[row])
    uint2 sr = *(const uint2*)(Hb + (unsigned)node * 32u + (unsigned)q * 8u);
    float2 s0 = __half22float2(*(const __half2*)&sr.x);
    float2 s1 = __half22float2(*(const __half2*)&sr.y);
    float a0 = s0.x, a1 = s0.y, a2 = s1.x, a3 = s1.y;
    float c0 = 0.f, c1 = 0.f, c2 = 0.f, c3 = 0.f;

    int j = 0;
    if (n > 0) {
        int nm1 = n - 1;
        int idxc[8];
#pragma unroll
        for (int u = 0; u < 8; ++u) {
            int e = (u < nm1) ? u : nm1;
            idxc[u] = __builtin_nontemporal_load(
                (const int*)(Cb + (unsigned)((start + e) << 2)));
        }
        for (; j + 8 <= n; j += 8) {
            uint2 hr[8];
#pragma unroll
            for (int u = 0; u < 8; ++u)
                hr[u] = *(const uint2*)(Hb + ((unsigned)idxc[u] * 32u + (unsigned)q * 8u));
            int idxn[8];
#pragma unroll
            for (int u = 0; u < 8; ++u) {
                int e = j + 8 + u;
                e = (e < nm1) ? e : nm1;
                idxn[u] = __builtin_nontemporal_load(
                    (const int*)(Cb + (unsigned)((start + e) << 2)));
            }
            __builtin_amdgcn_sched_barrier(0);   // keep all 16 loads before consumes
#pragma unroll
            for (int u = 0; u < 8; ++u) {
                float2 h0 = __half22float2(*(const __half2*)&hr[u].x);
                float2 h1 = __half22float2(*(const __half2*)&hr[u].y);
                if (u & 1) { c0 += h0.x; c1 += h0.y; c2 += h1.x; c3 += h1.y; }
                else       { a0 += h0.x; a1 += h0.y; a2 += h1.x; a3 += h1.y; }
            }
#pragma unroll
            for (int u = 0; u < 8; ++u) idxc[u] = idxn[u];
        }
        if (j < n) {                          // masked tail batch (idxc pre-clamped)
            uint2 hr[8];
#pragma unroll
            for (int u = 0; u < 8; ++u)
                hr[u] = *(const uint2*)(Hb + ((unsigned)idxc[u] * 32u + (unsigned)q * 8u));
            __builtin_amdgcn_sched_barrier(0);
#pragma unroll
            for (int u = 0; u < 8; ++u) {
                float m = (j + u < n) ? 1.0f : 0.0f;
                float2 h0 = __half22float2(*(const __half2*)&hr[u].x);
                float2 h1 = __half22float2(*(const __half2*)&hr[u].y);
                a0 = fmaf(h0.x, m, a0); a1 = fmaf(h0.y, m, a1);
                a2 = fmaf(h1.x, m, a2); a3 = fmaf(h1.y, m, a3);
            }
        }
    }
    a0 += c0; a1 += c1; a2 += c2; a3 += c3;

    f4v v;
    v.x = fmaxf(fmaf(a0, dd, bb.x), 0.0f);
    v.y = fmaxf(fmaf(a1, dd, bb.y), 0.0f);
    v.z = fmaxf(fmaf(a2, dd, bb.z), 0.0f);
    v.w = fmaxf(fmaf(a3, dd, bb.w), 0.0f);
    float* op = std_out ? (out + (size_t)node * 128 + s * 16 + q * 4)
                        : (out + ((size_t)s * N_NODES + node) * 16 + q * 4);
    __builtin_nontemporal_store(v, (f4v*)op);
}

// ---------------- launch ----------------

extern "C" void kernel_launch(void* const* d_in, const int* in_sizes, int n_in,
                              void* d_out, int out_size, void* d_ws, size_t ws_size,
                              hipStream_t stream) {
    const float* x  = (const float*)d_in[0];
    const int*   ei = (const int*)d_in[1];   // int32: [0,E)=src, [E,2E)=dst
    const float* Wm[3] = {(const float*)d_in[2], (const float*)d_in[4], (const float*)d_in[6]};
    const float* bv[3] = {(const float*)d_in[3], (const float*)d_in[5], (const float*)d_in[7]};
    float* out = (float*)d_out;

    char* w = (char*)d_ws;
    int*      row_ptr     = (int*)(w + 0);            // 0.4 MB
    int*      cnt         = (int*)(w + 400384);       // 0.4 MB
    float*    dinv        = (float*)(w + 800768);     // 0.4 MB
    int*      bucket_cnt  = (int*)(w + 1201152);      // 2 KB
    int*      bucket_base = (int*)(w + 1203200);      // 2 KB
    int*      bucket_fill = (int*)(w + 1205248);      // 2 KB
    unsigned* bpairs      = (unsigned*)(w + 1207296); // 12.8 MB
    int*      csr_src     = (int*)(w + 14007808);     // 12.8 MB
    short*    fragHi      = (short*)(w + 26808320);   // 96 KB (3 layers)
    short*    fragLo      = (short*)(w + 26906624);   // 96 KB
    __half*   H16         = (__half*)(w + 27004928);  // 25.6 MB sliced (total ~52.6 MB)

    // W repack (+ fused bucket zero), then bucketed counting-sort CSR build
    k_wprep<<<193, 256, 0, stream>>>(Wm[0], Wm[1], Wm[2], fragHi, fragLo, bucket_cnt);
    k_bhist<<<NCHUNKB, 256, 0, stream>>>(ei + N_EDGES, bucket_cnt);
    k_bscan<<<1, 512, 0, stream>>>(bucket_cnt, bucket_base, bucket_fill);
    k_bscatter<<<NCHUNKB, 256, 0, stream>>>(ei, bucket_fill, bpairs);
    k_bbuild<<<NBUCKETS, 256, 0, stream>>>(bpairs, bucket_base, row_ptr, cnt, dinv, csr_src);

    // 3 GCN layers; d_out doubles as the (sliced) fp32 ping buffer
    const float* xin = x;
    for (int l = 0; l < 3; ++l) {
        k_gemm_mfma<<<(N_NODES + 127) / 128, 512, 0, stream>>>(xin, fragHi + l * 16384,
                                                               fragLo + l * 16384, dinv, H16,
                                                               l > 0);
        k_gather<<<8 * NGB, 256, 0, stream>>>((const __half2*)H16, csr_src,
                                              row_ptr, cnt, dinv, bv[l], out,
                                              l == 2);
        xin = out;
    }
}

// Round 5
// 585.854 us; speedup vs baseline: 2.1989x; 2.1989x over previous
//
#include <hip/hip_runtime.h>
#include <hip/hip_fp16.h>

#define N_NODES 100000
#define N_EDGES 3200000
#define NBUCKETS 391          // ceil(100000 / 256); bucket = dst >> 8
#define NCHUNKB 256           // blocks for hist/scatter
#define CHUNK 12500           // N_EDGES / NCHUNKB
// FEATURE == HIDDEN == 128
// edge_index arrives as int32: ei[0..E) = src, ei[E..2E) = dst.

typedef __attribute__((ext_vector_type(8))) short sh8;   // 8 bf16 (4 VGPRs)
typedef __attribute__((ext_vector_type(4))) float fl4;   // MFMA acc

// split fp32 into bf16 hi + bf16 lo (both round-to-nearest-even)
__device__ inline void split_bf16(float x, short& hi, short& lo) {
    unsigned u = __float_as_uint(x);
    unsigned r = u + 0x7FFFu + ((u >> 16) & 1u);
    hi = (short)(r >> 16);
    float hif = __uint_as_float(r & 0xFFFF0000u);
    float lof = x - hif;
    unsigned u2 = __float_as_uint(lof);
    lo = (short)((u2 + 0x7FFFu + ((u2 >> 16) & 1u)) >> 16);
}

// ---------------- bucketed CSR build ----------------

__global__ __launch_bounds__(256) void k_bhist(const int* __restrict__ ei_dst,
                                               int* __restrict__ bucket_cnt) {
    __shared__ int h[NBUCKETS];
    int t = threadIdx.x;
    for (int i = t; i < NBUCKETS; i += 256) h[i] = 0;
    __syncthreads();
    int base = blockIdx.x * CHUNK;
    for (int i = t; i < CHUNK; i += 256)
        atomicAdd(&h[ei_dst[base + i] >> 8], 1);
    __syncthreads();
    for (int i = t; i < NBUCKETS; i += 256)
        if (h[i]) atomicAdd(&bucket_cnt[i], h[i]);
}

__global__ __launch_bounds__(512) void k_bscan(const int* __restrict__ bucket_cnt,
                                               int* __restrict__ bucket_base,
                                               int* __restrict__ bucket_fill) {
    __shared__ int s[512];
    int t = threadIdx.x;
    int v = (t < NBUCKETS) ? bucket_cnt[t] : 0;
    s[t] = v;
    __syncthreads();
    for (int off = 1; off < 512; off <<= 1) {
        int x = (t >= off) ? s[t - off] : 0;
        __syncthreads();
        s[t] += x;
        __syncthreads();
    }
    int ex = s[t] - v;
    if (t < NBUCKETS) { bucket_base[t] = ex; bucket_fill[t] = ex; }
    if (t == NBUCKETS - 1) bucket_base[NBUCKETS] = s[t];
}

// packed entry: src (17 bits) | dstlocal (8 bits) << 17
__global__ __launch_bounds__(256) void k_bscatter(const int* __restrict__ ei,
                                                  int* __restrict__ bucket_fill,
                                                  unsigned* __restrict__ bpairs) {
    __shared__ int h[NBUCKETS];
    __shared__ int basep[NBUCKETS];
    int t = threadIdx.x;
    const int* dstp = ei + N_EDGES;
    int base = blockIdx.x * CHUNK;

    for (int i = t; i < NBUCKETS; i += 256) h[i] = 0;
    __syncthreads();
    for (int i = t; i < CHUNK; i += 256)
        atomicAdd(&h[dstp[base + i] >> 8], 1);
    __syncthreads();
    for (int i = t; i < NBUCKETS; i += 256) {
        int c = h[i];
        basep[i] = c ? atomicAdd(&bucket_fill[i], c) : 0;
    }
    __syncthreads();
    for (int i = t; i < NBUCKETS; i += 256) h[i] = 0;  // reuse as rank
    __syncthreads();
    for (int i = t; i < CHUNK; i += 256) {
        int d = dstp[base + i];
        int s = ei[base + i];
        int b = d >> 8;
        int r = atomicAdd(&h[b], 1);
        bpairs[basep[b] + r] = (unsigned)s | ((unsigned)(d & 255) << 17);
    }
}

__global__ __launch_bounds__(256) void k_bbuild(const unsigned* __restrict__ bpairs,
                                                const int* __restrict__ bucket_base,
                                                int* __restrict__ row_ptr,
                                                int* __restrict__ cnt,
                                                float* __restrict__ dinv,
                                                int* __restrict__ csr_src) {
    __shared__ int h[256];
    __shared__ int sc[256];
    int b = blockIdx.x;
    int t = threadIdx.x;
    int e0 = bucket_base[b], e1 = bucket_base[b + 1];

    h[t] = 0;
    __syncthreads();
    for (int i = e0 + t; i < e1; i += 256)
        atomicAdd(&h[bpairs[i] >> 17], 1);
    __syncthreads();
    int v = h[t];
    sc[t] = v;
    __syncthreads();
    for (int off = 1; off < 256; off <<= 1) {
        int x = (t >= off) ? sc[t - off] : 0;
        __syncthreads();
        sc[t] += x;
        __syncthreads();
    }
    int ex = sc[t] - v;
    int node = b * 256 + t;
    if (node < N_NODES) {
        cnt[node] = v;
        dinv[node] = rsqrtf((float)(v + 1));
        row_ptr[node] = e0 + ex;
    }
    __syncthreads();
    h[t] = e0 + ex;               // absolute fill cursor
    __syncthreads();
    for (int i = e0 + t; i < e1; i += 256) {
        unsigned p = bpairs[i];
        int pos = atomicAdd(&h[p >> 17], 1);
        csr_src[pos] = (int)(p & 0x1FFFFu);
    }
}

// ------- W repack (+ fused bucket_cnt zero in the extra block) -------
// B-frag (16x16x32): lane = q*16 + n16 holds B[k = ks*32 + q*8 + j][n = c*16 + n16],
// j = 0..7 contiguous. Storage: frag[((l*32 + ks*8 + c)*64 + lane)*8 + j].

__global__ __launch_bounds__(256) void k_wprep(const float* __restrict__ W0,
                                               const float* __restrict__ W1,
                                               const float* __restrict__ W2,
                                               short* __restrict__ fhi,
                                               short* __restrict__ flo,
                                               int* __restrict__ bucket_cnt) {
    if (blockIdx.x == 192) {   // fused: zero the bucket counters
        for (int i = threadIdx.x; i < NBUCKETS; i += 256) bucket_cnt[i] = 0;
        return;
    }
    int idx = blockIdx.x * 256 + threadIdx.x;   // 3 * 16384
    int l = idx >> 14, e = idx & 16383;
    const float* W = (l == 0) ? W0 : (l == 1) ? W1 : W2;
    float w = W[e];
    int k = e >> 7, n = e & 127;
    int ks = k >> 5, q = (k >> 3) & 3, j = k & 7;
    int c = n >> 4, n16 = n & 15;
    int lane = q * 16 + n16;
    int dst = ((l * 32 + ks * 8 + c) * 64 + lane) * 8 + j;
    short hi, lo;
    split_bf16(w, hi, lo);
    fhi[dst] = hi;
    flo[dst] = lo;
}

// ------- GEMM v4: H16 = fp16( (X @ W) * dinv[row] ) via split-bf16 MFMA -------
// Row-major H16 [node][128]. 512 threads = 8 waves, 1 row-tile (16 rows) per wave.

__global__ __launch_bounds__(512, 4) void k_gemm_mfma(const float* __restrict__ X,
                                                      const short* __restrict__ fhi,
                                                      const short* __restrict__ flo,
                                                      const float* __restrict__ dinv,
                                                      __half* __restrict__ H16) {
    __shared__ short Bh[16384];    // 32 KB
    __shared__ short Bl[16384];    // 32 KB

    int t = threadIdx.x;
    int wave = t >> 6, lane = t & 63;
    int q = lane >> 4, n16 = lane & 15;
    int row_base = blockIdx.x * 128 + wave * 16;

    // hoist all A loads: 4 ks x 32 B per lane (in flight before any use)
    int r0 = row_base + n16;
    if (r0 > N_NODES - 1) r0 = N_NODES - 1;
    const float* p0 = X + (long long)r0 * 128 + q * 8;
    float4 a[4][2];
#pragma unroll
    for (int ks = 0; ks < 4; ++ks) {
        a[ks][0] = *(const float4*)(p0 + ks * 32);
        a[ks][1] = *(const float4*)(p0 + ks * 32 + 4);
    }

    // stage B frags into LDS: 2048 float4 per array, 512 threads -> 4 iters
    {
        const float4* sh_ = (const float4*)fhi;
        const float4* sl_ = (const float4*)flo;
        float4* dh = (float4*)Bh;
        float4* dl = (float4*)Bl;
#pragma unroll
        for (int i = 0; i < 4; ++i) {
            dh[t + i * 512] = sh_[t + i * 512];
            dl[t + i * 512] = sl_[t + i * 512];
        }
    }

    // split A into bf16 hi/lo fragments (under vmcnt shadow)
    sh8 ah[4], al[4];
#pragma unroll
    for (int ks = 0; ks < 4; ++ks) {
        float xs[8];
        xs[0] = a[ks][0].x; xs[1] = a[ks][0].y; xs[2] = a[ks][0].z; xs[3] = a[ks][0].w;
        xs[4] = a[ks][1].x; xs[5] = a[ks][1].y; xs[6] = a[ks][1].z; xs[7] = a[ks][1].w;
#pragma unroll
        for (int j = 0; j < 8; ++j) {
            short h, l;
            split_bf16(xs[j], h, l);
            ah[ks][j] = h;
            al[ks][j] = l;
        }
    }

    fl4 acc[8];
#pragma unroll
    for (int c = 0; c < 8; ++c) acc[c] = (fl4){0.f, 0.f, 0.f, 0.f};

    __syncthreads();

    // MFMA loop: pure LDS reads + MFMA (compiler pipelines via lgkmcnt)
#pragma unroll
    for (int ks = 0; ks < 4; ++ks)
#pragma unroll
        for (int c = 0; c < 8; ++c) {
            sh8 bh = *(const sh8*)&Bh[((ks * 8 + c) * 64 + lane) * 8];
            sh8 bl = *(const sh8*)&Bl[((ks * 8 + c) * 64 + lane) * 8];
            acc[c] = __builtin_amdgcn_mfma_f32_16x16x32_bf16(ah[ks], bh, acc[c], 0, 0, 0);
            acc[c] = __builtin_amdgcn_mfma_f32_16x16x32_bf16(al[ks], bh, acc[c], 0, 0, 0);
            acc[c] = __builtin_amdgcn_mfma_f32_16x16x32_bf16(ah[ks], bl, acc[c], 0, 0, 0);
        }

    // epilogue: C/D layout row = q*4 + reg, col = c*16 + n16
#pragma unroll
    for (int reg = 0; reg < 4; ++reg) {
        int grow = row_base + q * 4 + reg;
        if (grow < N_NODES) {
            float sc = dinv[grow];
            __half* dst = H16 + (long long)grow * 128 + n16;
#pragma unroll
            for (int c = 0; c < 8; ++c)
                dst[c * 16] = __float2half(acc[c][reg] * sc);
        }
    }
}

// ---------------- gather aggregation + bias + relu (wide-load, row-major) --------
// 1 node per wave; 16 lanes per edge row: lane = sub*16 + fc, sub = edge slot
// (0..3), fc = feature chunk (16 B = 8 halfs). One uint4 load fetches a full
// 256 B row per 16-lane group -> 4 rows per instruction, 4x fewer VMEM ops than
// the half2 version. 16 edges per iteration (4 uint4 + 4 idx loads in flight,
// sched_barrier(0) pins consumes after the load cluster). Clamp+mask, no
// branches in the loop; idx prefetched one batch ahead. No nontemporal.

__device__ inline void acc8(const uint4& h, float m, float* a) {
    float2 f0 = __half22float2(*(const __half2*)&h.x);
    float2 f1 = __half22float2(*(const __half2*)&h.y);
    float2 f2 = __half22float2(*(const __half2*)&h.z);
    float2 f3 = __half22float2(*(const __half2*)&h.w);
    a[0] = fmaf(f0.x, m, a[0]); a[1] = fmaf(f0.y, m, a[1]);
    a[2] = fmaf(f1.x, m, a[2]); a[3] = fmaf(f1.y, m, a[3]);
    a[4] = fmaf(f2.x, m, a[4]); a[5] = fmaf(f2.y, m, a[5]);
    a[6] = fmaf(f3.x, m, a[6]); a[7] = fmaf(f3.y, m, a[7]);
}

__global__ __launch_bounds__(256) void k_gather(const __half* __restrict__ H,
                                                const int* __restrict__ csr_src,
                                                const int* __restrict__ row_ptr,
                                                const int* __restrict__ cnt,
                                                const float* __restrict__ dinv,
                                                const float* __restrict__ b,
                                                float* __restrict__ out) {
    int wv = __builtin_amdgcn_readfirstlane(threadIdx.x >> 6);
    int node = blockIdx.x * 4 + wv;
    int lane = threadIdx.x & 63;
    int sub = lane >> 4;              // edge slot 0..3
    int fc  = lane & 15;              // feature chunk: halfs [fc*8, fc*8+8)
    if (node >= N_NODES) return;

    int start = row_ptr[node];
    int n = cnt[node];
    float dd = dinv[node];
    float2 bb = ((const float2*)b)[fc * 4 + sub];

    const char* Hb = (const char*)H;

    float acc[8];
#pragma unroll
    for (int i = 0; i < 8; ++i) acc[i] = 0.0f;

    // self contribution (H row already carries dinv[row]); only sub 0 adds it
    {
        uint4 sr = *(const uint4*)(Hb + (size_t)node * 256 + fc * 16);
        acc8(sr, (sub == 0) ? 1.0f : 0.0f, acc);
    }

    if (n > 0) {
        int nm1 = n - 1;
        int e;
        int i0, i1, i2, i3;
        e = sub;      i0 = csr_src[start + ((e < nm1) ? e : nm1)];
        e = 4 + sub;  i1 = csr_src[start + ((e < nm1) ? e : nm1)];
        e = 8 + sub;  i2 = csr_src[start + ((e < nm1) ? e : nm1)];
        e = 12 + sub; i3 = csr_src[start + ((e < nm1) ? e : nm1)];

        for (int j = 0; j < n; j += 16) {
            uint4 h0 = *(const uint4*)(Hb + (size_t)(unsigned)i0 * 256 + fc * 16);
            uint4 h1 = *(const uint4*)(Hb + (size_t)(unsigned)i1 * 256 + fc * 16);
            uint4 h2 = *(const uint4*)(Hb + (size_t)(unsigned)i2 * 256 + fc * 16);
            uint4 h3 = *(const uint4*)(Hb + (size_t)(unsigned)i3 * 256 + fc * 16);
            int jn = j + 16;
            int n0, n1, n2, n3;
            e = jn + sub;      n0 = csr_src[start + ((e < nm1) ? e : nm1)];
            e = jn + 4 + sub;  n1 = csr_src[start + ((e < nm1) ? e : nm1)];
            e = jn + 8 + sub;  n2 = csr_src[start + ((e < nm1) ? e : nm1)];
            e = jn + 12 + sub; n3 = csr_src[start + ((e < nm1) ? e : nm1)];
            __builtin_amdgcn_sched_barrier(0);   // loads stay clustered before consumes
            float m0 = (j + sub      < n) ? 1.0f : 0.0f;
            float m1 = (j + 4 + sub  < n) ? 1.0f : 0.0f;
            float m2 = (j + 8 + sub  < n) ? 1.0f : 0.0f;
            float m3 = (j + 12 + sub < n) ? 1.0f : 0.0f;
            acc8(h0, m0, acc);
            acc8(h1, m1, acc);
            acc8(h2, m2, acc);
            acc8(h3, m3, acc);
            i0 = n0; i1 = n1; i2 = n2; i3 = n3;
        }
    }

    // reduce across the 4 edge slots (lanes l, l^16, l^32, l^48)
#pragma unroll
    for (int i = 0; i < 8; ++i) {
        acc[i] += __shfl_xor(acc[i], 16, 64);
        acc[i] += __shfl_xor(acc[i], 32, 64);
    }

    // each sub stores its pair of the 8 features (static selection, no scratch)
    float sx = acc[0], sy = acc[1];
    if (sub == 1) { sx = acc[2]; sy = acc[3]; }
    if (sub == 2) { sx = acc[4]; sy = acc[5]; }
    if (sub == 3) { sx = acc[6]; sy = acc[7]; }

    float2 v;
    v.x = fmaxf(fmaf(sx, dd, bb.x), 0.0f);
    v.y = fmaxf(fmaf(sy, dd, bb.y), 0.0f);
    ((float2*)out)[node * 64 + fc * 4 + sub] = v;
}

// ---------------- launch ----------------

extern "C" void kernel_launch(void* const* d_in, const int* in_sizes, int n_in,
                              void* d_out, int out_size, void* d_ws, size_t ws_size,
                              hipStream_t stream) {
    const float* x  = (const float*)d_in[0];
    const int*   ei = (const int*)d_in[1];   // int32: [0,E)=src, [E,2E)=dst
    const float* Wm[3] = {(const float*)d_in[2], (const float*)d_in[4], (const float*)d_in[6]};
    const float* bv[3] = {(const float*)d_in[3], (const float*)d_in[5], (const float*)d_in[7]};
    float* out = (float*)d_out;

    char* w = (char*)d_ws;
    int*      row_ptr     = (int*)(w + 0);            // 0.4 MB
    int*      cnt         = (int*)(w + 400384);       // 0.4 MB
    float*    dinv        = (float*)(w + 800768);     // 0.4 MB
    int*      bucket_cnt  = (int*)(w + 1201152);      // 2 KB
    int*      bucket_base = (int*)(w + 1203200);      // 2 KB
    int*      bucket_fill = (int*)(w + 1205248);      // 2 KB
    unsigned* bpairs      = (unsigned*)(w + 1207296); // 12.8 MB
    int*      csr_src     = (int*)(w + 14007808);     // 12.8 MB
    short*    fragHi      = (short*)(w + 26808320);   // 96 KB (3 layers)
    short*    fragLo      = (short*)(w + 26906624);   // 96 KB
    __half*   H16         = (__half*)(w + 27004928);  // 25.6 MB row-major

    // W repack (+ fused bucket zero), then bucketed counting-sort CSR build
    k_wprep<<<193, 256, 0, stream>>>(Wm[0], Wm[1], Wm[2], fragHi, fragLo, bucket_cnt);
    k_bhist<<<NCHUNKB, 256, 0, stream>>>(ei + N_EDGES, bucket_cnt);
    k_bscan<<<1, 512, 0, stream>>>(bucket_cnt, bucket_base, bucket_fill);
    k_bscatter<<<NCHUNKB, 256, 0, stream>>>(ei, bucket_fill, bpairs);
    k_bbuild<<<NBUCKETS, 256, 0, stream>>>(bpairs, bucket_base, row_ptr, cnt, dinv, csr_src);

    // 3 GCN layers; d_out doubles as the fp32 ping buffer
    const float* xin = x;
    for (int l = 0; l < 3; ++l) {
        k_gemm_mfma<<<(N_NODES + 127) / 128, 512, 0, stream>>>(xin, fragHi + l * 16384,
                                                               fragLo + l * 16384, dinv, H16);
        k_gather<<<(N_NODES + 3) / 4, 256, 0, stream>>>(H16, csr_src,
                                                        row_ptr, cnt, dinv, bv[l], out);
        xin = out;
    }
}